// Round 1
// baseline (223.668 us; speedup 1.0000x reference)
//
#include <hip/hip_runtime.h>
#include <hip/hip_cooperative_groups.h>

namespace cg = cooperative_groups;

#define AN 256
#define BN 64
#define DN 768
#define LN 2
#define G1N 4
#define G2N 8
#define KI (DN / 32)   // 24 k-iterations of 32

typedef __attribute__((ext_vector_type(8))) short short8;   // 8 bf16
typedef __attribute__((ext_vector_type(4))) short bf16x4;   // 4 bf16
typedef __attribute__((ext_vector_type(4))) float floatx4;  // MFMA acc

static __device__ __forceinline__ unsigned short f2bf(float f) {
    union { float f; unsigned int u; } v; v.f = f;
    unsigned int r = v.u + 0x7FFF + ((v.u >> 16) & 1);  // RNE
    return (unsigned short)(r >> 16);
}

struct Params {
    const float* __restrict__ pooled;
    const float* __restrict__ W1;
    const float* __restrict__ b1;
    const float* __restrict__ W2;
    const float* __restrict__ b2;
    const float* __restrict__ Wh;
    const float* __restrict__ bh;
    const int*   __restrict__ g1i;
    const int*   __restrict__ g2i;
    float*       __restrict__ out;
    unsigned short* __restrict__ W1t;
    unsigned short* __restrict__ Whp;
    unsigned short* __restrict__ pooled_bf;
    float* __restrict__ bc;
    int*   __restrict__ n1;
    int*   __restrict__ n2;
    int*   __restrict__ lst1;
    int*   __restrict__ sidx2;
    unsigned short* __restrict__ h1;
    unsigned short* __restrict__ Wcs;
};

// ---------------------------------------------------------------------------
// Phase 1 jobs (identical bodies to the old k_prep; bx = job index 0..840):
//   bx <  576 : W1 transpose tile -> W1t[g][e][d] bf16
//   576..583  : pooled->bf16 slice + bc for 32 annotators
//   bx == 584 : g1 lists (n1,lst1), n2 counts, sidx2 LUT
//   585..840  : pack Wh[a] -> Whp[(g2*128+s)*2+l][e] bf16
// ---------------------------------------------------------------------------
static __device__ __forceinline__ void prep_job(int bx, const Params& p) {
    const int tid = threadIdx.x;

    if (bx < 576) {
        const int g = bx / 144, t = bx % 144;
        const int d0 = (t / 12) * 64, e0 = (t % 12) * 64;
        const float* src = p.W1 + (size_t)g * DN * DN;
        __shared__ float tile[64][65];
        const int r = tid >> 4, c = (tid & 15) * 4;
        #pragma unroll
        for (int i = 0; i < 4; ++i) {
            float4 v = *(const float4*)(src + (size_t)(d0 + r + 16 * i) * DN + e0 + c);
            tile[r + 16 * i][c + 0] = v.x; tile[r + 16 * i][c + 1] = v.y;
            tile[r + 16 * i][c + 2] = v.z; tile[r + 16 * i][c + 3] = v.w;
        }
        __syncthreads();
        #pragma unroll
        for (int i = 0; i < 4; ++i) {
            bf16x4 v;
            #pragma unroll
            for (int j = 0; j < 4; ++j) v[j] = (short)f2bf(tile[c + j][r + 16 * i]);
            *(bf16x4*)(p.W1t + ((size_t)g * DN + e0 + r + 16 * i) * DN + d0 + c) = v;
        }
        return;
    }

    if (bx < 584) {
        const int i0 = (bx - 576) * 6144;
        for (int i = i0 + tid; i < i0 + 6144; i += 256)
            p.pooled_bf[i] = f2bf(p.pooled[i]);

        // bc: 32 annotators per job, 8 threads per annotator
        const int aa = tid >> 3, j = tid & 7;
        const int a = (bx - 576) * 32 + aa;
        const int gv2 = p.g2i[a];
        const float* whp = p.Wh + (size_t)a * (DN * LN);
        const float* b2p = p.b2 + gv2 * DN;
        float acc0 = 0.f, acc1 = 0.f;
        #pragma unroll 4
        for (int i = 0; i < 48; ++i) {
            int e = j * 96 + i * 2;
            float4 w4 = *(const float4*)(whp + e * 2);
            float2 bv = *(const float2*)(b2p + e);
            acc0 += bv.x * w4.x + bv.y * w4.z;
            acc1 += bv.x * w4.y + bv.y * w4.w;
        }
        #pragma unroll
        for (int off = 4; off; off >>= 1) {
            acc0 += __shfl_down(acc0, off, 64);
            acc1 += __shfl_down(acc1, off, 64);
        }
        if (j == 0) {
            p.bc[a * 2 + 0] = acc0 + p.bh[a * 2 + 0];
            p.bc[a * 2 + 1] = acc1 + p.bh[a * 2 + 1];
        }
        return;
    }

    if (bx == 584) {
        __shared__ int g1s[AN], g2s[AN];
        __shared__ int c1s[G1N], c2s[G2N];
        g1s[tid] = p.g1i[tid];
        g2s[tid] = p.g2i[tid];
        if (tid < G1N) c1s[tid] = 0;
        if (tid < G2N) c2s[tid] = 0;
        __syncthreads();
        int s = 0, my2 = g2s[tid];
        for (int a2 = 0; a2 < tid; ++a2) s += (g2s[a2] == my2);
        p.sidx2[tid] = s;
        atomicAdd(&c2s[my2], 1);
        int p1 = atomicAdd(&c1s[g1s[tid]], 1);
        p.lst1[g1s[tid] * 256 + p1] = tid;
        __syncthreads();
        if (tid < G1N) p.n1[tid] = c1s[tid];
        if (tid < G2N) p.n2[tid] = c2s[tid];
        return;
    }

    // ---- pack Wh[a] into Whp rows (g2-bucketed, l-de-interleaved) ----
    {
        const int a = bx - 585;
        __shared__ int g2s[AN];
        g2s[tid] = p.g2i[tid];
        __syncthreads();
        int s = 0, my2 = g2s[a];
        for (int a2 = 0; a2 < a; ++a2) s += (g2s[a2] == my2);
        const size_t rp = ((size_t)my2 * 128 + s) * 2;
        const float* wa = p.Wh + (size_t)a * (DN * LN);
        #pragma unroll
        for (int i = 0; i < 3; ++i) {
            int e = i * 256 + tid;
            float2 v = *(const float2*)(wa + e * 2);
            p.Whp[rp * DN + e]       = f2bf(v.x);
            p.Whp[(rp + 1) * DN + e] = f2bf(v.y);
        }
    }
}

// ---------------------------------------------------------------------------
// Phase 2 (old k_mid): bx in 0..11, by in 0..11. No LDS, no barriers.
// ---------------------------------------------------------------------------
static __device__ __forceinline__ void mid_job(int bx, int by, const Params& p) {
    const int tid  = threadIdx.x;
    const int lane = tid & 63, wave = tid >> 6;
    const int nn   = lane & 15, quad = lane >> 4;

    if (by < G1N) {
        // ---- h1 = pooled @ W1[g] + b1[g] ----
        const int g = by, e0 = bx * 64;
        const int e = e0 + wave * 16 + nn;
        const unsigned short* Bt = p.W1t + ((size_t)g * DN + e) * DN + quad * 8;
        const unsigned short* Ap = p.pooled_bf + (size_t)nn * DN + quad * 8;
        floatx4 acc[4] = {{0,0,0,0},{0,0,0,0},{0,0,0,0},{0,0,0,0}};
        #pragma unroll
        for (int kk = 0; kk < KI; ++kk) {
            short8 bf = *(const short8*)(Bt + kk * 32);
            #pragma unroll
            for (int mt = 0; mt < 4; ++mt) {
                short8 af = *(const short8*)(Ap + (size_t)(mt * 16) * DN + kk * 32);
                acc[mt] = __builtin_amdgcn_mfma_f32_16x16x32_bf16(af, bf, acc[mt], 0, 0, 0);
            }
        }
        const float bv = p.b1[g * DN + e];
        #pragma unroll
        for (int mt = 0; mt < 4; ++mt)
            #pragma unroll
            for (int r = 0; r < 4; ++r)
                p.h1[(size_t)g * BN * DN + (size_t)(mt * 16 + quad * 4 + r) * DN + e] =
                    f2bf(acc[mt][r] + bv);
    } else {
        // ---- Wc: A = W2 rows in regs; stream packed Whp columns ----
        const int g = by - G1N;
        const int mbase = bx * 64;
        const int cols = 2 * p.n2[g];
        const int m_row = mbase + wave * 16 + nn;

        const float* ap = p.W2 + ((size_t)g * DN + m_row) * DN + quad * 8;
        short8 Areg[KI];
        #pragma unroll
        for (int kk = 0; kk < KI; ++kk) {
            float4 a0 = *(const float4*)(ap + kk * 32);
            float4 a1 = *(const float4*)(ap + kk * 32 + 4);
            short8 af;
            af[0] = (short)f2bf(a0.x); af[1] = (short)f2bf(a0.y);
            af[2] = (short)f2bf(a0.z); af[3] = (short)f2bf(a0.w);
            af[4] = (short)f2bf(a1.x); af[5] = (short)f2bf(a1.y);
            af[6] = (short)f2bf(a1.z); af[7] = (short)f2bf(a1.w);
            Areg[kk] = af;
        }

        const unsigned short* Bbase = p.Whp + (size_t)(g * 256) * DN;
        for (int c0 = 0; c0 < cols; c0 += 16) {
            const unsigned short* Brow = Bbase + (size_t)(c0 + nn) * DN + quad * 8;
            floatx4 acc = {0, 0, 0, 0};
            #pragma unroll
            for (int kk = 0; kk < KI; ++kk) {
                short8 bf = *(const short8*)(Brow + kk * 32);
                acc = __builtin_amdgcn_mfma_f32_16x16x32_bf16(Areg[kk], bf, acc, 0, 0, 0);
            }
            const int c = c0 + nn;
            if (c < cols) {
                const int dbase = mbase + wave * 16 + quad * 4;
                bf16x4 v;
                #pragma unroll
                for (int r = 0; r < 4; ++r) v[r] = (short)f2bf(acc[r]);
                *(bf16x4*)(p.Wcs + (size_t)(g * 256 + c) * DN + dbase) = v;
            }
        }
    }
}

// ---------------------------------------------------------------------------
// Phase 3 (old k_last): bx in 0..31, by in 0..3; extra column-tiles exit early.
// ---------------------------------------------------------------------------
static __device__ __forceinline__ void last_job(int bx, int by, const Params& p) {
    const int g = by;
    const int cols = 2 * p.n1[g];
    const int nt0 = bx * 16;
    if (nt0 >= cols) return;

    const int tid = threadIdx.x;
    const int lane = tid & 63, wave = tid >> 6;
    const int nn = lane & 15, quad = lane >> 4;

    const int c = nt0 + nn;
    const bool valid = (c < cols);
    const int cl = valid ? c : (cols - 1);
    const int a = p.lst1[g * 256 + (cl >> 1)];
    const int l = cl & 1;
    const int rp = (p.g2i[a] * 128 + p.sidx2[a]) * 2 + l;

    const unsigned short* hg = p.h1 + (size_t)g * BN * DN + (size_t)(wave * 16 + nn) * DN + quad * 8;
    const unsigned short* wp = p.Wcs + (size_t)rp * DN + quad * 8;

    floatx4 acc = {0, 0, 0, 0};
    #pragma unroll
    for (int kk = 0; kk < KI; ++kk) {
        short8 af = *(const short8*)(hg + kk * 32);
        short8 bf = *(const short8*)(wp + kk * 32);
        acc = __builtin_amdgcn_mfma_f32_16x16x32_bf16(af, bf, acc, 0, 0, 0);
    }
    if (valid) {
        const float bv = p.bc[a * 2 + l];
        #pragma unroll
        for (int r = 0; r < 4; ++r)
            p.out[(size_t)(wave * 16 + quad * 4 + r) * (AN * LN) + a * 2 + l] = acc[r] + bv;
    }
}

// ---------------------------------------------------------------------------
// Fused cooperative kernel: 256 blocks x 256 threads (1 block/CU, trivially
// co-resident). Two grid syncs replace the two inter-kernel boundaries.
// ---------------------------------------------------------------------------
__global__ __launch_bounds__(256) void fused(Params p) {
    cg::grid_group grid = cg::this_grid();

    // ---- phase 1: 841 prep jobs, grid-strided ----
    for (int job = blockIdx.x; job < 841; job += 256) {
        prep_job(job, p);
        __syncthreads();   // LDS reuse guard between consecutive jobs
    }

    grid.sync();

    // ---- phase 2: old k_mid grid (12, 12) ----
    if (blockIdx.x < 144) mid_job(blockIdx.x % 12, blockIdx.x / 12, p);

    grid.sync();

    // ---- phase 3: old k_last grid (32, 4) ----
    if (blockIdx.x < 128) last_job(blockIdx.x & 31, blockIdx.x >> 5, p);
}

extern "C" void kernel_launch(void* const* d_in, const int* in_sizes, int n_in,
                              void* d_out, int out_size, void* d_ws, size_t ws_size,
                              hipStream_t stream) {
    Params p;
    p.pooled = (const float*)d_in[0];
    p.W1     = (const float*)d_in[1];
    p.b1     = (const float*)d_in[2];
    p.W2     = (const float*)d_in[3];
    p.b2     = (const float*)d_in[4];
    p.Wh     = (const float*)d_in[5];
    p.bh     = (const float*)d_in[6];
    p.g1i    = (const int*)d_in[7];
    p.g2i    = (const int*)d_in[8];
    p.out    = (float*)d_out;

    // Workspace carve (all chunks 16B-multiple): ~11.7 MB total
    char* ws = (char*)d_ws;
    p.bc    = (float*)ws;             ws += 512 * 4;
    p.n1    = (int*)ws;               ws += 4 * 4;
    p.n2    = (int*)ws;               ws += 8 * 4;
    p.lst1  = (int*)ws;               ws += 4 * 256 * 4;
    p.sidx2 = (int*)ws;               ws += 256 * 4;
    p.pooled_bf = (unsigned short*)ws;  ws += (size_t)BN * DN * 2;
    p.h1        = (unsigned short*)ws;  ws += (size_t)G1N * BN * DN * 2;
    p.W1t       = (unsigned short*)ws;  ws += (size_t)G1N * DN * DN * 2;
    p.Whp       = (unsigned short*)ws;  ws += (size_t)G2N * 256 * DN * 2;
    p.Wcs       = (unsigned short*)ws;

    void* args[] = { (void*)&p };
    (void)hipLaunchCooperativeKernel((const void*)fused, dim3(256), dim3(256),
                                     args, 0, stream);
}

// Round 4
// 134.998 us; speedup vs baseline: 1.6568x; 1.6568x over previous
//
#include <hip/hip_runtime.h>
#include <hip/hip_bf16.h>

#define AN 256
#define BN 64
#define DN 768
#define LN 2
#define G1N 4
#define G2N 8
#define KI (DN / 32)   // 24 k-iterations of 32

typedef __attribute__((ext_vector_type(8))) short short8;   // 8 bf16
typedef __attribute__((ext_vector_type(4))) short bf16x4;   // 4 bf16
typedef __attribute__((ext_vector_type(4))) float floatx4;  // MFMA acc

static __device__ __forceinline__ unsigned short f2bf(float f) {
    union { float f; unsigned int u; } v; v.f = f;
    unsigned int r = v.u + 0x7FFF + ((v.u >> 16) & 1);  // RNE
    return (unsigned short)(r >> 16);
}

// ---------------------------------------------------------------------------
// k_prep: 265 blocks x 256. The 576 W1-transpose tiles are GONE (k_mid now
// reads W1 transposed directly). Remaining jobs, bodies verbatim-baseline:
//   bx < 8  : pooled->bf16 slice + bc for 32 annotators
//   bx == 8 : g1 lists (n1,lst1), n2 counts, sidx2 LUT
//   bx >= 9 : pack Wh[a] -> Whp[(g2*128+s)*2+l][e] bf16  (a = bx-9)
// ---------------------------------------------------------------------------
__global__ __launch_bounds__(256) void k_prep(
    const float* __restrict__ pooled,
    const float* __restrict__ b2, const float* __restrict__ Wh,
    const float* __restrict__ bh,
    const int* __restrict__ g1i, const int* __restrict__ g2i,
    unsigned short* __restrict__ Whp,
    unsigned short* __restrict__ pooled_bf, float* __restrict__ bc,
    int* __restrict__ n1, int* __restrict__ n2,
    int* __restrict__ lst1, int* __restrict__ sidx2)
{
    const int tid = threadIdx.x, bx = blockIdx.x;

    if (bx < 8) {
        const int i0 = bx * 6144;
        for (int i = i0 + tid; i < i0 + 6144; i += 256)
            pooled_bf[i] = f2bf(pooled[i]);

        // bc: 32 annotators per block, 8 threads per annotator
        const int aa = tid >> 3, j = tid & 7;
        const int a = bx * 32 + aa;
        const int gv2 = g2i[a];
        const float* whp = Wh + (size_t)a * (DN * LN);
        const float* b2p = b2 + gv2 * DN;
        float acc0 = 0.f, acc1 = 0.f;
        #pragma unroll 4
        for (int i = 0; i < 48; ++i) {
            int e = j * 96 + i * 2;
            float4 w4 = *(const float4*)(whp + e * 2);
            float2 bv = *(const float2*)(b2p + e);
            acc0 += bv.x * w4.x + bv.y * w4.z;
            acc1 += bv.x * w4.y + bv.y * w4.w;
        }
        #pragma unroll
        for (int off = 4; off; off >>= 1) {
            acc0 += __shfl_down(acc0, off, 64);
            acc1 += __shfl_down(acc1, off, 64);
        }
        if (j == 0) {
            bc[a * 2 + 0] = acc0 + bh[a * 2 + 0];
            bc[a * 2 + 1] = acc1 + bh[a * 2 + 1];
        }
        return;
    }

    if (bx == 8) {
        __shared__ int g1s[AN], g2s[AN];
        __shared__ int c1s[G1N], c2s[G2N];
        g1s[tid] = g1i[tid];
        g2s[tid] = g2i[tid];
        if (tid < G1N) c1s[tid] = 0;
        if (tid < G2N) c2s[tid] = 0;
        __syncthreads();
        // deterministic sidx2 (must match pack blocks' computation)
        int s = 0, my2 = g2s[tid];
        for (int a2 = 0; a2 < tid; ++a2) s += (g2s[a2] == my2);
        sidx2[tid] = s;
        atomicAdd(&c2s[my2], 1);
        int p1 = atomicAdd(&c1s[g1s[tid]], 1);
        lst1[g1s[tid] * 256 + p1] = tid;
        __syncthreads();
        if (tid < G1N) n1[tid] = c1s[tid];
        if (tid < G2N) n2[tid] = c2s[tid];
        return;
    }

    // ---- pack Wh[a] into Whp rows (g2-bucketed, l-de-interleaved) ----
    {
        const int a = bx - 9;
        __shared__ int g2s[AN];
        g2s[tid] = g2i[tid];
        __syncthreads();
        int s = 0, my2 = g2s[a];
        for (int a2 = 0; a2 < a; ++a2) s += (g2s[a2] == my2);
        const size_t rp = ((size_t)my2 * 128 + s) * 2;
        const float* wa = Wh + (size_t)a * (DN * LN);
        #pragma unroll
        for (int i = 0; i < 3; ++i) {
            int e = i * 256 + tid;
            float2 v = *(const float2*)(wa + e * 2);
            Whp[rp * DN + e]       = f2bf(v.x);
            Whp[(rp + 1) * DN + e] = f2bf(v.y);
        }
    }
}

// ---------------------------------------------------------------------------
// k_mid: 144 blocks x 256. No LDS, no barriers.
//  bx <  48: h1[g][b][e] = pooled @ W1[g] + b1[g]; B-fragment read DIRECTLY
//            from W1 (transposed gather: 8 dword loads per k-step, each 64B
//            line shared by 16 lanes; all loads independent -> ILP-hidden).
//            Identical rounding to the old W1t path: f2bf(W1[g][k][e]).
//  bx >= 48: Wc for g2 group: Wcs[g*256+c][d] = sum_e W2[g][d,e]*Whp[..c..][e]
//            (verbatim baseline body; A = W2 rows held in VGPRs)
// ---------------------------------------------------------------------------
__global__ __launch_bounds__(256) void k_mid(
    const float* __restrict__ W1, const float* __restrict__ W2,
    const float* __restrict__ b1,
    const unsigned short* __restrict__ Whp,
    const unsigned short* __restrict__ pooled_bf,
    const int* __restrict__ n2,
    unsigned short* __restrict__ h1, unsigned short* __restrict__ Wcs)
{
    const int tid  = threadIdx.x;
    const int lane = tid & 63, wave = tid >> 6;
    const int nn   = lane & 15, quad = lane >> 4;
    const int bx   = blockIdx.x;

    if (bx < 48) {
        // ---- h1 = pooled @ W1[g] + b1[g], W1 columns gathered on the fly ----
        const int g = bx / 12, e0 = (bx % 12) * 64;
        const int e = e0 + wave * 16 + nn;
        const float* Wcol = W1 + (size_t)g * DN * DN + e;   // column e, stride DN
        const unsigned short* Ap = pooled_bf + (size_t)nn * DN + quad * 8;
        floatx4 acc[4] = {{0,0,0,0},{0,0,0,0},{0,0,0,0},{0,0,0,0}};
        #pragma unroll
        for (int kk = 0; kk < KI; ++kk) {
            const float* wk = Wcol + (size_t)(kk * 32 + quad * 8) * DN;
            short8 bf;
            #pragma unroll
            for (int j = 0; j < 8; ++j)
                bf[j] = (short)f2bf(wk[(size_t)j * DN]);
            #pragma unroll
            for (int mt = 0; mt < 4; ++mt) {
                short8 af = *(const short8*)(Ap + (size_t)(mt * 16) * DN + kk * 32);
                acc[mt] = __builtin_amdgcn_mfma_f32_16x16x32_bf16(af, bf, acc[mt], 0, 0, 0);
            }
        }
        const float bv = b1[g * DN + e];
        #pragma unroll
        for (int mt = 0; mt < 4; ++mt)
            #pragma unroll
            for (int r = 0; r < 4; ++r)
                h1[(size_t)g * BN * DN + (size_t)(mt * 16 + quad * 4 + r) * DN + e] =
                    f2bf(acc[mt][r] + bv);
    } else {
        // ---- Wc: A = W2 rows in regs; stream packed Whp columns ----
        const int j = bx - 48;
        const int g = j / 12;
        const int mbase = (j % 12) * 64;
        const int cols = 2 * n2[g];
        const int m_row = mbase + wave * 16 + nn;

        const float* ap = W2 + ((size_t)g * DN + m_row) * DN + quad * 8;
        short8 Areg[KI];
        #pragma unroll
        for (int kk = 0; kk < KI; ++kk) {
            float4 a0 = *(const float4*)(ap + kk * 32);
            float4 a1 = *(const float4*)(ap + kk * 32 + 4);
            short8 af;
            af[0] = (short)f2bf(a0.x); af[1] = (short)f2bf(a0.y);
            af[2] = (short)f2bf(a0.z); af[3] = (short)f2bf(a0.w);
            af[4] = (short)f2bf(a1.x); af[5] = (short)f2bf(a1.y);
            af[6] = (short)f2bf(a1.z); af[7] = (short)f2bf(a1.w);
            Areg[kk] = af;
        }

        const unsigned short* Bbase = Whp + (size_t)(g * 256) * DN;
        for (int c0 = 0; c0 < cols; c0 += 16) {
            const unsigned short* Brow = Bbase + (size_t)(c0 + nn) * DN + quad * 8;
            floatx4 acc = {0, 0, 0, 0};
            #pragma unroll
            for (int kk = 0; kk < KI; ++kk) {
                short8 bf = *(const short8*)(Brow + kk * 32);
                acc = __builtin_amdgcn_mfma_f32_16x16x32_bf16(Areg[kk], bf, acc, 0, 0, 0);
            }
            const int c = c0 + nn;
            if (c < cols) {
                const int dbase = mbase + wave * 16 + quad * 4;
                bf16x4 v;
                #pragma unroll
                for (int r = 0; r < 4; ++r) v[r] = (short)f2bf(acc[r]);
                *(bf16x4*)(Wcs + (size_t)(g * 256 + c) * DN + dbase) = v;
            }
        }
    }
}

// ---------------------------------------------------------------------------
// k_last: out[b, a, l] = h1[g1(a)][b,:] . Wcs[(g2(a)*128+s2(a))*2+l][:] + bc
// grid = (32, 4) x 256; extra column-tiles exit early. (verbatim baseline)
// ---------------------------------------------------------------------------
__global__ __launch_bounds__(256) void k_last(
    const unsigned short* __restrict__ h1, const unsigned short* __restrict__ Wcs,
    const float* __restrict__ bc, const int* __restrict__ n1,
    const int* __restrict__ lst1, const int* __restrict__ sidx2,
    const int* __restrict__ g2i, float* __restrict__ out)
{
    const int g = blockIdx.y;
    const int cols = 2 * n1[g];
    const int nt0 = blockIdx.x * 16;
    if (nt0 >= cols) return;

    const int tid = threadIdx.x;
    const int lane = tid & 63, wave = tid >> 6;
    const int nn = lane & 15, quad = lane >> 4;

    const int c = nt0 + nn;
    const bool valid = (c < cols);
    const int cl = valid ? c : (cols - 1);
    const int a = lst1[g * 256 + (cl >> 1)];
    const int l = cl & 1;
    const int rp = (g2i[a] * 128 + sidx2[a]) * 2 + l;

    const unsigned short* hg = h1 + (size_t)g * BN * DN + (size_t)(wave * 16 + nn) * DN + quad * 8;
    const unsigned short* wp = Wcs + (size_t)rp * DN + quad * 8;

    floatx4 acc = {0, 0, 0, 0};
    #pragma unroll
    for (int kk = 0; kk < KI; ++kk) {
        short8 af = *(const short8*)(hg + kk * 32);
        short8 bf = *(const short8*)(wp + kk * 32);
        acc = __builtin_amdgcn_mfma_f32_16x16x32_bf16(af, bf, acc, 0, 0, 0);
    }
    if (valid) {
        const float bv = bc[a * 2 + l];
        #pragma unroll
        for (int r = 0; r < 4; ++r)
            out[(size_t)(wave * 16 + quad * 4 + r) * (AN * LN) + a * 2 + l] = acc[r] + bv;
    }
}

extern "C" void kernel_launch(void* const* d_in, const int* in_sizes, int n_in,
                              void* d_out, int out_size, void* d_ws, size_t ws_size,
                              hipStream_t stream) {
    const float* pooled = (const float*)d_in[0];
    const float* W1     = (const float*)d_in[1];
    const float* b1     = (const float*)d_in[2];
    const float* W2     = (const float*)d_in[3];
    const float* b2     = (const float*)d_in[4];
    const float* Wh     = (const float*)d_in[5];
    const float* bh     = (const float*)d_in[6];
    const int*   g1i    = (const int*)d_in[7];
    const int*   g2i    = (const int*)d_in[8];
    float* out = (float*)d_out;

    // Workspace carve (all chunks 16B-multiple): ~7 MB (no W1t any more)
    char* ws = (char*)d_ws;
    float* bc   = (float*)ws;             ws += 512 * 4;
    int*   n1   = (int*)ws;               ws += 4 * 4;
    int*   n2   = (int*)ws;               ws += 8 * 4;
    int*   lst1 = (int*)ws;               ws += 4 * 256 * 4;
    int*   sidx2= (int*)ws;               ws += 256 * 4;
    unsigned short* pooled_bf = (unsigned short*)ws;  ws += (size_t)BN * DN * 2;
    unsigned short* h1        = (unsigned short*)ws;  ws += (size_t)G1N * BN * DN * 2;
    unsigned short* Whp       = (unsigned short*)ws;  ws += (size_t)G2N * 256 * DN * 2;
    unsigned short* Wcs       = (unsigned short*)ws;

    dim3 blk(256);
    k_prep<<<dim3(265),   blk, 0, stream>>>(pooled, b2, Wh, bh, g1i, g2i,
                                            Whp, pooled_bf, bc, n1, n2, lst1, sidx2);
    k_mid <<<dim3(144),   blk, 0, stream>>>(W1, W2, b1, Whp, pooled_bf, n2, h1, Wcs);
    k_last<<<dim3(32, 4), blk, 0, stream>>>(h1, Wcs, bc, n1, lst1, sidx2, g2i, out);
}

// Round 5
// 116.444 us; speedup vs baseline: 1.9208x; 1.1593x over previous
//
#include <hip/hip_runtime.h>

#define AN 256
#define BN 64
#define DN 768
#define LN 2
#define G1N 4
#define G2N 8
#define KI (DN / 32)   // 24 k-iterations of 32
#define PAD 776        // 768 + 8 bf16 pad -> 1552B row stride (4-bank shift/row, 2-way max = free)

typedef __attribute__((ext_vector_type(8))) short short8;   // 8 bf16
typedef __attribute__((ext_vector_type(4))) short bf16x4;   // 4 bf16
typedef __attribute__((ext_vector_type(4))) float floatx4;  // MFMA acc

static __device__ __forceinline__ unsigned short f2bf(float f) {
    union { float f; unsigned int u; } v; v.f = f;
    unsigned int r = v.u + 0x7FFF + ((v.u >> 16) & 1);  // RNE
    return (unsigned short)(r >> 16);
}
static __device__ __forceinline__ unsigned int pack2(float a, float b) {
    return (unsigned int)f2bf(a) | ((unsigned int)f2bf(b) << 16);
}

// ---------------------------------------------------------------------------
// k_main: 152 blocks x 256. Fully self-sufficient blocks (no prep kernel):
//   bx <  48 : h1[g][b][e-tile] = pooled @ W1[g] + b1[g].
//              pooled staged once -> LDS bf16 [64][PAD]; B gathered from W1
//              (transposed reads, same rounding as old W1t path).
//   48..143  : Wc for g2 group g=(bx-48)/12: in-block rank-scan of g2i gives
//              the annotator list; per-16-col tile, stage Wh -> LDS bf16
//              (coalesced float4), then Areg(W2) x LDS MFMA -> Wcs.
//   144..151 : bc for 32 annotators (verbatim baseline body).
// ---------------------------------------------------------------------------
__global__ __launch_bounds__(256) void k_main(
    const float* __restrict__ pooled, const float* __restrict__ W1,
    const float* __restrict__ b1, const float* __restrict__ W2,
    const float* __restrict__ b2, const float* __restrict__ Wh,
    const float* __restrict__ bh, const int* __restrict__ g2i,
    unsigned short* __restrict__ h1, unsigned short* __restrict__ Wcs,
    float* __restrict__ bc)
{
    __shared__ __align__(16) unsigned char smem[64 * PAD * 2];   // 99328 B, role-unioned
    const int tid = threadIdx.x, bx = blockIdx.x;
    const int lane = tid & 63, wave = tid >> 6;
    const int nn = lane & 15, quad = lane >> 4;

    if (bx < 48) {
        // ---------------- h1 role ----------------
        unsigned short* ps = (unsigned short*)smem;              // [64][PAD] bf16
        {
            const float4* p4 = (const float4*)pooled;            // 12288 float4
            #pragma unroll
            for (int i = 0; i < 48; ++i) {
                const int idx = i * 256 + tid;
                float4 v = p4[idx];
                const int row = idx / 192, c4 = idx % 192;
                const unsigned long long w =
                    (unsigned long long)pack2(v.x, v.y) |
                    ((unsigned long long)pack2(v.z, v.w) << 32);
                *(unsigned long long*)(ps + row * PAD + c4 * 4) = w;
            }
        }
        __syncthreads();

        const int g = bx / 12, e0 = (bx % 12) * 64;
        const int e = e0 + wave * 16 + nn;
        const float* Wcol = W1 + (size_t)g * DN * DN + e;        // column e, stride DN
        const unsigned short* Ap = ps + nn * PAD + quad * 8;
        floatx4 acc[4] = {{0,0,0,0},{0,0,0,0},{0,0,0,0},{0,0,0,0}};
        #pragma unroll
        for (int kk = 0; kk < KI; ++kk) {
            const float* wk = Wcol + (size_t)(kk * 32 + quad * 8) * DN;
            short8 bf;
            #pragma unroll
            for (int j = 0; j < 8; ++j)
                bf[j] = (short)f2bf(wk[(size_t)j * DN]);
            #pragma unroll
            for (int mt = 0; mt < 4; ++mt) {
                short8 af = *(const short8*)(Ap + (mt * 16) * PAD + kk * 32);
                acc[mt] = __builtin_amdgcn_mfma_f32_16x16x32_bf16(af, bf, acc[mt], 0, 0, 0);
            }
        }
        const float bv = b1[g * DN + e];
        #pragma unroll
        for (int mt = 0; mt < 4; ++mt)
            #pragma unroll
            for (int r = 0; r < 4; ++r)
                h1[(size_t)g * BN * DN + (size_t)(mt * 16 + quad * 4 + r) * DN + e] =
                    f2bf(acc[mt][r] + bv);
    } else if (bx < 144) {
        // ---------------- Wc role ----------------
        int* g2s  = (int*)smem;                                  // [256]
        int* lst2 = (int*)(smem + 1024);                         // [256]
        unsigned short* Whs = (unsigned short*)(smem + 2048);    // [16][PAD] bf16

        const int j = bx - 48, g = j / 12, mbase = (j % 12) * 64;

        // A = W2 rows -> regs (issue the big loads first; scan overlaps latency)
        const int m_row = mbase + wave * 16 + nn;
        const float* ap = W2 + ((size_t)g * DN + m_row) * DN + quad * 8;
        short8 Areg[KI];
        #pragma unroll
        for (int kk = 0; kk < KI; ++kk) {
            float4 a0 = *(const float4*)(ap + kk * 32);
            float4 a1 = *(const float4*)(ap + kk * 32 + 4);
            short8 af;
            af[0] = (short)f2bf(a0.x); af[1] = (short)f2bf(a0.y);
            af[2] = (short)f2bf(a0.z); af[3] = (short)f2bf(a0.w);
            af[4] = (short)f2bf(a1.x); af[5] = (short)f2bf(a1.y);
            af[6] = (short)f2bf(a1.z); af[7] = (short)f2bf(a1.w);
            Areg[kk] = af;
        }

        // in-block index scan: deterministic rank within g2 group
        g2s[tid] = g2i[tid];
        __syncthreads();
        const int my = g2s[tid];
        int rk = 0;
        for (int a2 = 0; a2 < tid; ++a2) rk += (g2s[a2] == my);
        if (my == g) lst2[rk] = tid;
        int n2g = 0;
        for (int a2 = 0; a2 < AN; ++a2) n2g += (g2s[a2] == g);
        __syncthreads();
        const int cols = 2 * n2g;

        const int al = tid >> 5, t32 = tid & 31;
        for (int c0 = 0; c0 < cols; c0 += 16) {
            // stage 8 annotators' Wh columns -> Whs[16][PAD] (l-de-interleaved)
            const int sidx = (c0 >> 1) + al;
            if (sidx < n2g) {
                const int a = lst2[sidx];
                const float4* wa4 = (const float4*)(Wh + (size_t)a * (DN * LN));
                #pragma unroll
                for (int i = 0; i < 12; ++i) {
                    const int f4 = i * 32 + t32;          // 0..383
                    float4 v = wa4[f4];
                    const int e2 = f4 * 2;                // elems e2, e2+1
                    *(unsigned int*)(Whs + (2 * al)     * PAD + e2) = pack2(v.x, v.z);
                    *(unsigned int*)(Whs + (2 * al + 1) * PAD + e2) = pack2(v.y, v.w);
                }
            }
            __syncthreads();
            const unsigned short* Brow = Whs + nn * PAD + quad * 8;
            floatx4 acc = {0, 0, 0, 0};
            #pragma unroll
            for (int kk = 0; kk < KI; ++kk) {
                short8 bf = *(const short8*)(Brow + kk * 32);
                acc = __builtin_amdgcn_mfma_f32_16x16x32_bf16(Areg[kk], bf, acc, 0, 0, 0);
            }
            const int c = c0 + nn;
            if (c < cols) {
                const int dbase = mbase + wave * 16 + quad * 4;
                bf16x4 v;
                #pragma unroll
                for (int r = 0; r < 4; ++r) v[r] = (short)f2bf(acc[r]);
                *(bf16x4*)(Wcs + (size_t)(g * 256 + c) * DN + dbase) = v;
            }
            __syncthreads();   // reads done before next tile's staging
        }
    } else {
        // ---------------- bc role (verbatim baseline) ----------------
        const int jb = bx - 144;
        const int aa = tid >> 3, jj = tid & 7;
        const int a = jb * 32 + aa;
        const int gv2 = g2i[a];
        const float* whp = Wh + (size_t)a * (DN * LN);
        const float* b2p = b2 + gv2 * DN;
        float acc0 = 0.f, acc1 = 0.f;
        #pragma unroll 4
        for (int i = 0; i < 48; ++i) {
            int e = jj * 96 + i * 2;
            float4 w4 = *(const float4*)(whp + e * 2);
            float2 bv = *(const float2*)(b2p + e);
            acc0 += bv.x * w4.x + bv.y * w4.z;
            acc1 += bv.x * w4.y + bv.y * w4.w;
        }
        #pragma unroll
        for (int off = 4; off; off >>= 1) {
            acc0 += __shfl_down(acc0, off, 64);
            acc1 += __shfl_down(acc1, off, 64);
        }
        if (jj == 0) {
            bc[a * 2 + 0] = acc0 + bh[a * 2 + 0];
            bc[a * 2 + 1] = acc1 + bh[a * 2 + 1];
        }
    }
}

// ---------------------------------------------------------------------------
// k_out: grid (32, 4) x 256. Index lists computed in-block (rank-scan of
// g1i/g2i, deterministic -> matches k_main's Wcs column placement), then
// verbatim last body: out[b,a,l] = h1[g1(a)][b,:] . Wcs[..] + bc.
// ---------------------------------------------------------------------------
__global__ __launch_bounds__(256) void k_out(
    const unsigned short* __restrict__ h1, const unsigned short* __restrict__ Wcs,
    const float* __restrict__ bc, const int* __restrict__ g1i,
    const int* __restrict__ g2i, float* __restrict__ out)
{
    __shared__ int g1s[AN], g2s[AN], lst1[AN], sx2[AN];
    const int g = blockIdx.y;
    const int tid = threadIdx.x;
    g1s[tid] = g1i[tid];
    g2s[tid] = g2i[tid];
    __syncthreads();
    const int m1 = g1s[tid], m2 = g2s[tid];
    int r1 = 0, r2 = 0;
    for (int a2 = 0; a2 < tid; ++a2) {
        r1 += (g1s[a2] == m1);
        r2 += (g2s[a2] == m2);
    }
    sx2[tid] = r2;
    if (m1 == g) lst1[r1] = tid;
    int n1g = 0;
    for (int a2 = 0; a2 < AN; ++a2) n1g += (g1s[a2] == g);
    __syncthreads();

    const int cols = 2 * n1g;
    const int nt0 = blockIdx.x * 16;
    if (nt0 >= cols) return;

    const int lane = tid & 63, wave = tid >> 6;
    const int nn = lane & 15, quad = lane >> 4;

    const int c = nt0 + nn;
    const bool valid = (c < cols);
    const int cl = valid ? c : (cols - 1);
    const int a = lst1[cl >> 1];
    const int l = cl & 1;
    const int rp = (g2s[a] * 128 + sx2[a]) * 2 + l;

    const unsigned short* hg = h1 + (size_t)g * BN * DN + (size_t)(wave * 16 + nn) * DN + quad * 8;
    const unsigned short* wp = Wcs + (size_t)rp * DN + quad * 8;

    floatx4 acc = {0, 0, 0, 0};
    #pragma unroll
    for (int kk = 0; kk < KI; ++kk) {
        short8 af = *(const short8*)(hg + kk * 32);
        short8 bf = *(const short8*)(wp + kk * 32);
        acc = __builtin_amdgcn_mfma_f32_16x16x32_bf16(af, bf, acc, 0, 0, 0);
    }
    if (valid) {
        const float bv = bc[a * 2 + l];
        #pragma unroll
        for (int r = 0; r < 4; ++r)
            out[(size_t)(wave * 16 + quad * 4 + r) * (AN * LN) + a * 2 + l] = acc[r] + bv;
    }
}

extern "C" void kernel_launch(void* const* d_in, const int* in_sizes, int n_in,
                              void* d_out, int out_size, void* d_ws, size_t ws_size,
                              hipStream_t stream) {
    const float* pooled = (const float*)d_in[0];
    const float* W1     = (const float*)d_in[1];
    const float* b1     = (const float*)d_in[2];
    const float* W2     = (const float*)d_in[3];
    const float* b2     = (const float*)d_in[4];
    const float* Wh     = (const float*)d_in[5];
    const float* bh     = (const float*)d_in[6];
    const int*   g1i    = (const int*)d_in[7];
    const int*   g2i    = (const int*)d_in[8];
    float* out = (float*)d_out;

    // Workspace carve (16B multiples): bc + h1 + Wcs ~= 3.5 MB
    char* ws = (char*)d_ws;
    float* bc = (float*)ws;                           ws += 512 * 4;
    unsigned short* h1  = (unsigned short*)ws;        ws += (size_t)G1N * BN * DN * 2;
    unsigned short* Wcs = (unsigned short*)ws;

    dim3 blk(256);
    k_main<<<dim3(152),   blk, 0, stream>>>(pooled, W1, b1, W2, b2, Wh, bh, g2i,
                                            h1, Wcs, bc);
    k_out <<<dim3(32, 4), blk, 0, stream>>>(h1, Wcs, bc, g1i, g2i, out);
}